// Round 6
// baseline (381.185 us; speedup 1.0000x reference)
//
#include <hip/hip_runtime.h>
#include <hip/hip_bf16.h>
#include <stdint.h>

#define N_ROWS 32768
#define K_CB   4096
#define D_DIM  256
#define WINDOW 1.25e-4f
#define CSTR   65   // candidate LDS row stride (pad to break 32-way bank conflict)

typedef __attribute__((ext_vector_type(8))) short bf16x8;
typedef __attribute__((ext_vector_type(4))) float f32x4;

typedef const __attribute__((address_space(1))) void gvoid_t;
typedef __attribute__((address_space(3))) void lvoid_t;

// ---------------------------------------------------------------------------
// Replicate numpy's pairwise fp32 sum of squares for n=256: two 128-blocks
// (8 accumulators, 8-way unrolled, combine ((r0+r1)+(r2+r3))+((r4+r5)+(r6+r7))),
// then left+right.  fp contract OFF: numpy materializes fl(x*x) then adds —
// an FMA would change the rounding.  float4 loads, scalar-identical order.
// ---------------------------------------------------------------------------
__device__ float np_pairwise_sumsq_256(const float4* __restrict__ a4) {
#pragma clang fp contract(off)
    float s[2];
#pragma unroll
    for (int h = 0; h < 2; ++h) {
        const float4* b4 = a4 + h * 32;
        float r[8];
        {
            float4 v0 = b4[0], v1 = b4[1];
            r[0] = v0.x * v0.x; r[1] = v0.y * v0.y;
            r[2] = v0.z * v0.z; r[3] = v0.w * v0.w;
            r[4] = v1.x * v1.x; r[5] = v1.y * v1.y;
            r[6] = v1.z * v1.z; r[7] = v1.w * v1.w;
        }
        for (int i = 2; i < 32; i += 2) {
            float4 v0 = b4[i], v1 = b4[i + 1];
            r[0] = r[0] + v0.x * v0.x; r[1] = r[1] + v0.y * v0.y;
            r[2] = r[2] + v0.z * v0.z; r[3] = r[3] + v0.w * v0.w;
            r[4] = r[4] + v1.x * v1.x; r[5] = r[5] + v1.y * v1.y;
            r[6] = r[6] + v1.z * v1.z; r[7] = r[7] + v1.w * v1.w;
        }
        s[h] = ((r[0] + r[1]) + (r[2] + r[3])) + ((r[4] + r[5]) + (r[6] + r[7]));
    }
    return s[0] + s[1];
}

__global__ __launch_bounds__(256) void prep_np(const float* __restrict__ x,
                                               const float* __restrict__ e,
                                               float* __restrict__ L2np,
                                               float* __restrict__ C2np) {
    const int i = blockIdx.x * 256 + threadIdx.x;
    if (i < N_ROWS) {
        L2np[i] = np_pairwise_sumsq_256(reinterpret_cast<const float4*>(x) + (size_t)i * 64);
    } else if (i < N_ROWS + K_CB) {
        const int k = i - N_ROWS;
        C2np[k] = np_pairwise_sumsq_256(reinterpret_cast<const float4*>(e) + (size_t)k * 64);
    }
}

// ---------------------------------------------------------------------------
// Replicated-fp32 distance for one (row, k), packed for lex-min:
// CL = sequential-K fp32 FMA (BLAS sgemm microkernels accumulate each k step
// into the same C register in order);
// d  = fl32(L2 - 2*CL) + C2  (2*CL exact; matches np's (L2 - 2.0*CL) + C2).
// d ~ 256 > 0 so fp32 bits are order-monotone -> pack (bits<<32)|k;
// min pack == (min d, then min k) == np.argmin first-occurrence ties.
// ---------------------------------------------------------------------------
__device__ __forceinline__ uint64_t precise_pack(const float4* __restrict__ x4,
                                                 const float4* __restrict__ e4,
                                                 float L2v, float C2v, int k) {
    float acc = 0.f;
    for (int d = 0; d < 64; ++d) {
        float4 xv = x4[d], ev = e4[d];
        acc = __builtin_fmaf(xv.x, ev.x, acc);
        acc = __builtin_fmaf(xv.y, ev.y, acc);
        acc = __builtin_fmaf(xv.z, ev.z, acc);
        acc = __builtin_fmaf(xv.w, ev.w, acc);
    }
    float dq;
    {
#pragma clang fp contract(off)
        float t2 = 2.f * acc;       // exact
        float t3 = L2v - t2;        // rounded once
        dq = t3 + C2v;              // rounded once
    }
    return ((uint64_t)__float_as_uint(dq) << 32) | (uint32_t)k;
}

// ---------------------------------------------------------------------------
// Prep: split emb_weight (K x 256 fp32) into bf16 hi/lo stored in an
// XOR-swizzled layout (16B granule g -> g ^ (k&7) within each 512B row).
// ---------------------------------------------------------------------------
__global__ __launch_bounds__(64) void prep_emb(const float* __restrict__ e,
                                               short* __restrict__ ehi,
                                               short* __restrict__ elo) {
    const int k = blockIdx.x;
    const int l = threadIdx.x;
    const float4 v = reinterpret_cast<const float4*>(e)[k * 64 + l];
    float f[4] = {v.x, v.y, v.z, v.w};
    short hs[4], ls[4];
#pragma unroll
    for (int j = 0; j < 4; ++j) {
        float xv = f[j];
        __hip_bfloat16 h = __float2bfloat16(xv);
        float hf = __bfloat162float(h);
        __hip_bfloat16 lo = __float2bfloat16(xv - hf);
        __builtin_memcpy(&hs[j], &h, 2);
        __builtin_memcpy(&ls[j], &lo, 2);
    }
    const int sg = ((l >> 1) ^ (k & 7));
    const int off = k * 256 + sg * 8 + (l & 1) * 4;
    *reinterpret_cast<short4*>(ehi + off) = make_short4(hs[0], hs[1], hs[2], hs[3]);
    *reinterpret_cast<short4*>(elo + off) = make_short4(ls[0], ls[1], ls[2], ls[3]);
}

// ---------------------------------------------------------------------------
// Main: 64 rows/block vs all 4096 entries.  bf16x3 MFMA approx scores
// (error ~1e-7) with per-lane/slot top-2 tracking -> 64 candidates/row in
// LDS -> candidates within WINDOW of the row's approx min (capture bound
// 7.2e-5 = 2*(quant grid 3.05e-5 + C2 shift); typ. ~1.1 cand/row) get the
// replicated-fp32 rescore -> lex-min -> fused gather.
// ---------------------------------------------------------------------------
__global__ __launch_bounds__(256, 2) void vq_main(
    const float* __restrict__ x, const float* __restrict__ e,
    const short* __restrict__ ehi, const short* __restrict__ elo,
    const float* __restrict__ C2np, const float* __restrict__ L2np,
    float* __restrict__ out) {

    __shared__ char lds_raw[65536];  // B chunk: hi [64][256] bf16 @0, lo @32768
    short* bh = reinterpret_cast<short*>(lds_raw);
    short* bl = reinterpret_cast<short*>(lds_raw + 32768);

    const int t = threadIdx.x;
    const int lane = t & 63;
    const int wid = t >> 6;
    const int wr = wid >> 1;   // row half (M)
    const int wc = wid & 1;    // col half of each chunk (N)
    const int blk = blockIdx.x;

    const int r16 = lane & 15;     // fragment row/col within 16
    const int kg  = lane >> 4;     // k-group (0..3), 8 contiguous elems each

    // ---- A fragments: load x from global, split to bf16 hi/lo in-register --
    bf16x8 a_hi[2][8], a_lo[2][8];
#pragma unroll
    for (int m = 0; m < 2; ++m) {
        const int grow = blk * 64 + wr * 32 + m * 16 + r16;
        const float* xrow = x + (size_t)grow * 256;
#pragma unroll
        for (int ks = 0; ks < 8; ++ks) {
            const float* p = xrow + ks * 32 + kg * 8;
            float4 v0 = *reinterpret_cast<const float4*>(p);
            float4 v1f = *reinterpret_cast<const float4*>(p + 4);
            float fv[8] = {v0.x, v0.y, v0.z, v0.w, v1f.x, v1f.y, v1f.z, v1f.w};
#pragma unroll
            for (int j = 0; j < 8; ++j) {
                float fx = fv[j];
                __hip_bfloat16 h = __float2bfloat16(fx);
                float hf = __bfloat162float(h);
                __hip_bfloat16 lo = __float2bfloat16(fx - hf);
                short hsv, lsv;
                __builtin_memcpy(&hsv, &h, 2);
                __builtin_memcpy(&lsv, &lo, 2);
                a_hi[m][ks][j] = hsv;
                a_lo[m][ks][j] = lsv;
            }
        }
    }

    // per-(lane,slot) top-2, lex-ordered
    float v1[2][4], v2[2][4];
    int   i1[2][4], i2[2][4];
#pragma unroll
    for (int m = 0; m < 2; ++m)
#pragma unroll
        for (int r = 0; r < 4; ++r) {
            v1[m][r] = __builtin_inff(); v2[m][r] = __builtin_inff();
            i1[m][r] = 0x7fffffff;       i2[m][r] = 0x7fffffff;
        }

    const char* srch_base = reinterpret_cast<const char*>(ehi);
    const char* srcl_base = reinterpret_cast<const char*>(elo);
    const int uoff = (t & ~63) * 16;  // wave-uniform LDS base (HW adds lane*16)

    for (int ch = 0; ch < 64; ++ch) {
        // ---- stage B chunk (64 cols x 256 bf16, hi + lo = 64KB) ----
        {
            const char* srch = srch_base + (size_t)ch * 32768;
            const char* srcl = srcl_base + (size_t)ch * 32768;
#pragma unroll
            for (int i = 0; i < 8; ++i) {
                const int so = i * 4096 + t * 16;
                const int uo = i * 4096 + uoff;
                __builtin_amdgcn_global_load_lds((gvoid_t*)(srch + so),
                                                 (lvoid_t*)(lds_raw + uo), 16, 0, 0);
                __builtin_amdgcn_global_load_lds((gvoid_t*)(srcl + so),
                                                 (lvoid_t*)(lds_raw + 32768 + uo), 16, 0, 0);
            }
        }
        __syncthreads();

        // ---- compute: 2 m-tiles x 2 n-tiles, K=256 in 8 slices of 32 ----
        f32x4 acc[2][2];
#pragma unroll
        for (int m = 0; m < 2; ++m)
#pragma unroll
            for (int n = 0; n < 2; ++n) acc[m][n] = (f32x4){0.f, 0.f, 0.f, 0.f};

#pragma unroll
        for (int ks = 0; ks < 8; ++ks) {
#pragma unroll
            for (int n = 0; n < 2; ++n) {
                const int col = wc * 32 + n * 16 + r16;            // within chunk
                const int sg = (ks * 4 + kg) ^ (col & 7);          // unswizzle
                const int boff = col * 256 + sg * 8;               // elems
                bf16x8 bh8 = *reinterpret_cast<const bf16x8*>(bh + boff);
                bf16x8 bl8 = *reinterpret_cast<const bf16x8*>(bl + boff);
#pragma unroll
                for (int m = 0; m < 2; ++m) {
                    acc[m][n] = __builtin_amdgcn_mfma_f32_16x16x32_bf16(a_hi[m][ks], bh8, acc[m][n], 0, 0, 0);
                    acc[m][n] = __builtin_amdgcn_mfma_f32_16x16x32_bf16(a_hi[m][ks], bl8, acc[m][n], 0, 0, 0);
                    acc[m][n] = __builtin_amdgcn_mfma_f32_16x16x32_bf16(a_lo[m][ks], bh8, acc[m][n], 0, 0, 0);
                }
            }
        }

        // ---- approx scores + running top-2 (acc row = kg*4+r, col = r16) ----
#pragma unroll
        for (int n = 0; n < 2; ++n) {
            const int colg = ch * 64 + wc * 32 + n * 16 + r16;
            const float c2v = C2np[colg];
#pragma unroll
            for (int m = 0; m < 2; ++m)
#pragma unroll
                for (int r = 0; r < 4; ++r) {
                    float d = __builtin_fmaf(-2.f, acc[m][n][r], c2v);
                    const bool lt1 = d < v1[m][r];
                    const bool lt2 = d < v2[m][r];
                    v2[m][r] = lt1 ? v1[m][r] : (lt2 ? d : v2[m][r]);
                    i2[m][r] = lt1 ? i1[m][r] : (lt2 ? colg : i2[m][r]);
                    v1[m][r] = lt1 ? d : v1[m][r];
                    i1[m][r] = lt1 ? colg : i1[m][r];
                }
        }
        __syncthreads();
    }

    // ---- dump 64 candidates/row to LDS (B region dead; stride CSTR=65) ----
    float* candV = reinterpret_cast<float*>(lds_raw);              // [64][65]
    int*   candI = reinterpret_cast<int*>(lds_raw + 64 * CSTR * 4);// [64][65]
    int*   winIdx = reinterpret_cast<int*>(lds_raw + 2 * 64 * CSTR * 4);  // [64]
#pragma unroll
    for (int m = 0; m < 2; ++m)
#pragma unroll
        for (int r = 0; r < 4; ++r) {
            const int rl = wr * 32 + m * 16 + kg * 4 + r;
            const int p = wc * 32 + r16 * 2;
            candV[rl * CSTR + p]     = v1[m][r];  candI[rl * CSTR + p]     = i1[m][r];
            candV[rl * CSTR + p + 1] = v2[m][r];  candI[rl * CSTR + p + 1] = i2[m][r];
        }
    __syncthreads();

    // ---- wave 0: per row, window-filter + replicated-fp32 rescore ----
    if (t < 64) {
        float mmin = candV[t * CSTR];
        for (int p = 1; p < 64; ++p) mmin = fminf(mmin, candV[t * CSTR + p]);
        const float wlim = mmin + WINDOW;
        const int grow = blk * 64 + t;
        const float L2v = L2np[grow];
        const float4* x4 = reinterpret_cast<const float4*>(x) + (size_t)grow * 64;
        uint64_t best = ~0ull;
        for (int p = 0; p < 64; ++p) {
            if (candV[t * CSTR + p] <= wlim) {
                const int k = candI[t * CSTR + p];
                const float4* e4 = reinterpret_cast<const float4*>(e) + (size_t)k * 64;
                uint64_t pk = precise_pack(x4, e4, L2v, C2np[k], k);
                best = best < pk ? best : pk;
            }
        }
        winIdx[t] = (int)(best & 0xffffffffu);
    }
    __syncthreads();

    // ---- gather winning codebook rows ----
    const float4* ef4 = reinterpret_cast<const float4*>(e);
    float4* of4 = reinterpret_cast<float4*>(out) + (size_t)blk * 64 * 64;
    for (int i = t; i < 64 * 64; i += 256) {
        const int row = i >> 6, c4 = i & 63;
        of4[i] = ef4[(size_t)winIdx[row] * 64 + c4];
    }
}

extern "C" void kernel_launch(void* const* d_in, const int* in_sizes, int n_in,
                              void* d_out, int out_size, void* d_ws, size_t ws_size,
                              hipStream_t stream) {
    const float* x = (const float*)d_in[0];
    const float* e = (const float*)d_in[1];
    char* ws = (char*)d_ws;
    short* ehi  = (short*)ws;                                   // 2 MB
    short* elo  = (short*)(ws + (size_t)K_CB * D_DIM * 2);      // 2 MB
    float* C2np = (float*)(ws + (size_t)K_CB * D_DIM * 4);      // 16 KB
    float* L2np = (float*)(ws + (size_t)K_CB * D_DIM * 4 + K_CB * 4);  // 128 KB
    float* out = (float*)d_out;

    prep_emb<<<K_CB, 64, 0, stream>>>(e, ehi, elo);
    prep_np<<<(N_ROWS + K_CB + 255) / 256, 256, 0, stream>>>(x, e, L2np, C2np);
    vq_main<<<N_ROWS / 64, 256, 0, stream>>>(x, e, ehi, elo, C2np, L2np, out);
}

// Round 10
// 342.503 us; speedup vs baseline: 1.1129x; 1.1129x over previous
//
#include <hip/hip_runtime.h>
#include <hip/hip_bf16.h>
#include <stdint.h>

#define N_ROWS 32768
#define K_CB   4096
#define D_DIM  256
#define WINDOW 1.5e-4f
#define CSTR   65   // candidate LDS row stride (pad to break bank conflicts)

typedef __attribute__((ext_vector_type(8))) short bf16x8;
typedef __attribute__((ext_vector_type(4))) float f32x4;

typedef const __attribute__((address_space(1))) void gvoid_t;
typedef __attribute__((address_space(3))) void lvoid_t;

// ---------------------------------------------------------------------------
// Replicate numpy's pairwise fp32 sum of squares for n=256 (bit-exact).
// ---------------------------------------------------------------------------
__device__ float np_pairwise_sumsq_256(const float4* __restrict__ a4) {
#pragma clang fp contract(off)
    float s[2];
#pragma unroll
    for (int h = 0; h < 2; ++h) {
        const float4* b4 = a4 + h * 32;
        float r[8];
        {
            float4 v0 = b4[0], v1 = b4[1];
            r[0] = v0.x * v0.x; r[1] = v0.y * v0.y;
            r[2] = v0.z * v0.z; r[3] = v0.w * v0.w;
            r[4] = v1.x * v1.x; r[5] = v1.y * v1.y;
            r[6] = v1.z * v1.z; r[7] = v1.w * v1.w;
        }
        for (int i = 2; i < 32; i += 2) {
            float4 v0 = b4[i], v1 = b4[i + 1];
            r[0] = r[0] + v0.x * v0.x; r[1] = r[1] + v0.y * v0.y;
            r[2] = r[2] + v0.z * v0.z; r[3] = r[3] + v0.w * v0.w;
            r[4] = r[4] + v1.x * v1.x; r[5] = r[5] + v1.y * v1.y;
            r[6] = r[6] + v1.z * v1.z; r[7] = r[7] + v1.w * v1.w;
        }
        s[h] = ((r[0] + r[1]) + (r[2] + r[3])) + ((r[4] + r[5]) + (r[6] + r[7]));
    }
    return s[0] + s[1];
}

__global__ __launch_bounds__(256) void prep_np(const float* __restrict__ x,
                                               const float* __restrict__ e,
                                               float* __restrict__ L2np,
                                               float* __restrict__ C2np) {
    const int i = blockIdx.x * 256 + threadIdx.x;
    if (i < N_ROWS) {
        L2np[i] = np_pairwise_sumsq_256(reinterpret_cast<const float4*>(x) + (size_t)i * 64);
    } else if (i < N_ROWS + K_CB) {
        const int k = i - N_ROWS;
        C2np[k] = np_pairwise_sumsq_256(reinterpret_cast<const float4*>(e) + (size_t)k * 64);
    }
}

// ---------------------------------------------------------------------------
// Replicated-fp32 distance (exact ref semantics), packed for lex-min.
// ---------------------------------------------------------------------------
__device__ __forceinline__ uint64_t precise_pack(const float4* __restrict__ x4,
                                                 const float4* __restrict__ e4,
                                                 float L2v, float C2v, int k) {
    float acc = 0.f;
    for (int d = 0; d < 64; ++d) {
        float4 xv = x4[d], ev = e4[d];
        acc = __builtin_fmaf(xv.x, ev.x, acc);
        acc = __builtin_fmaf(xv.y, ev.y, acc);
        acc = __builtin_fmaf(xv.z, ev.z, acc);
        acc = __builtin_fmaf(xv.w, ev.w, acc);
    }
    float dq;
    {
#pragma clang fp contract(off)
        float t2 = 2.f * acc;
        float t3 = L2v - t2;
        dq = t3 + C2v;
    }
    return ((uint64_t)__float_as_uint(dq) << 32) | (uint32_t)k;
}

// ---------------------------------------------------------------------------
// Prep: e -> single bf16 (RNE), XOR-swizzled granules (g ^ (k&7) per 512B row).
// ---------------------------------------------------------------------------
__global__ __launch_bounds__(64) void prep_emb(const float* __restrict__ e,
                                               short* __restrict__ ehi) {
    const int k = blockIdx.x;
    const int l = threadIdx.x;
    const float4 v = reinterpret_cast<const float4*>(e)[k * 64 + l];
    float f[4] = {v.x, v.y, v.z, v.w};
    short hs[4];
#pragma unroll
    for (int j = 0; j < 4; ++j) {
        __hip_bfloat16 h = __float2bfloat16(f[j]);
        __builtin_memcpy(&hs[j], &h, 2);
    }
    const int sg = ((l >> 1) ^ (k & 7));
    const int off = k * 256 + sg * 8 + (l & 1) * 4;
    *reinterpret_cast<short4*>(ehi + off) = make_short4(hs[0], hs[1], hs[2], hs[3]);
}

// ---------------------------------------------------------------------------
// Main: 64 rows/block vs all 4096 entries.  x split to bf16 hi/lo in regs
// (asm-pinned against remat); e single bf16 streamed through double-buffered
// LDS (32KB/chunk, STAGE(next) issued before compute(cur), 1 barrier/chunk).
// dot = xh.e + xl.e (2 MFMA); approx err sigma ~9e-6, capture bound 8.5e-5
// << WINDOW.  Per-slot top-2 -> window filter -> replicated-fp32 rescore ->
// lex-min -> fused gather.
// ---------------------------------------------------------------------------
__global__ __launch_bounds__(256, 2) void vq_main(
    const float* __restrict__ x, const float* __restrict__ e,
    const short* __restrict__ ehi,
    const float* __restrict__ C2np, const float* __restrict__ L2np,
    float* __restrict__ out) {

    __shared__ char lds_raw[65536];  // B dbuf: buf0 @0, buf1 @32768

    const int t = threadIdx.x;
    const int lane = t & 63;
    const int wid = t >> 6;
    const int wr = wid >> 1;   // row half (M)
    const int wc = wid & 1;    // col half of chunk (N)
    const int blk = blockIdx.x;

    const int r16 = lane & 15;
    const int kg  = lane >> 4;

    // ---- A fragments: x -> bf16 hi/lo, register-resident for whole kernel --
    bf16x8 a_hi[2][8], a_lo[2][8];
#pragma unroll
    for (int m = 0; m < 2; ++m) {
        const int grow = blk * 64 + wr * 32 + m * 16 + r16;
        const float* xrow = x + (size_t)grow * 256;
#pragma unroll
        for (int ks = 0; ks < 8; ++ks) {
            const float* p = xrow + ks * 32 + kg * 8;
            float4 v0 = *reinterpret_cast<const float4*>(p);
            float4 v1f = *reinterpret_cast<const float4*>(p + 4);
            float fv[8] = {v0.x, v0.y, v0.z, v0.w, v1f.x, v1f.y, v1f.z, v1f.w};
#pragma unroll
            for (int j = 0; j < 8; ++j) {
                float fx = fv[j];
                __hip_bfloat16 h = __float2bfloat16(fx);
                float hf = __bfloat162float(h);
                __hip_bfloat16 lo = __float2bfloat16(fx - hf);
                short hsv, lsv;
                __builtin_memcpy(&hsv, &h, 2);
                __builtin_memcpy(&lsv, &lo, 2);
                a_hi[m][ks][j] = hsv;
                a_lo[m][ks][j] = lsv;
            }
        }
    }
    // Pin fragments in VGPRs: opaque redefinition forbids rematerialization
    // (round-6 evidence: VGPR_Count=112 < 176 live => compiler was re-loading
    //  x + re-converting every chunk; this is the fix).
#pragma unroll
    for (int m = 0; m < 2; ++m)
#pragma unroll
        for (int ks = 0; ks < 8; ++ks) {
            asm volatile("" : "+v"(a_hi[m][ks]));
            asm volatile("" : "+v"(a_lo[m][ks]));
        }

    // per-(lane,slot) top-2, lex-ordered
    float v1[2][4], v2[2][4];
    int   i1[2][4], i2[2][4];
#pragma unroll
    for (int m = 0; m < 2; ++m)
#pragma unroll
        for (int r = 0; r < 4; ++r) {
            v1[m][r] = __builtin_inff(); v2[m][r] = __builtin_inff();
            i1[m][r] = 0x7fffffff;       i2[m][r] = 0x7fffffff;
        }

    const char* src_base = reinterpret_cast<const char*>(ehi);
    const int uoff = (t & ~63) * 16;  // wave-uniform LDS base (HW adds lane*16)
    const short* bh = reinterpret_cast<short*>(lds_raw);

#define STAGE(buf, ch_)                                                         \
    {                                                                           \
        const char* src = src_base + (size_t)(ch_) * 32768;                     \
        _Pragma("unroll")                                                       \
        for (int i_ = 0; i_ < 8; ++i_) {                                        \
            const int o_ = i_ * 4096;                                           \
            __builtin_amdgcn_global_load_lds((gvoid_t*)(src + o_ + t * 16),     \
                (lvoid_t*)(lds_raw + (buf) * 32768 + o_ + uoff), 16, 0, 0);     \
        }                                                                       \
    }

    STAGE(0, 0);
    __syncthreads();

    for (int ch = 0; ch < 64; ++ch) {
        const int cur = ch & 1;
        if (ch + 1 < 64) STAGE(cur ^ 1, ch + 1);

        f32x4 acc[2][2];
#pragma unroll
        for (int m = 0; m < 2; ++m)
#pragma unroll
            for (int n = 0; n < 2; ++n) acc[m][n] = (f32x4){0.f, 0.f, 0.f, 0.f};

        const int bufoff = cur * 16384;  // in shorts
#pragma unroll
        for (int ks = 0; ks < 8; ++ks) {
#pragma unroll
            for (int n = 0; n < 2; ++n) {
                const int col = wc * 32 + n * 16 + r16;
                const int sg = (ks * 4 + kg) ^ (col & 7);
                bf16x8 bh8 = *reinterpret_cast<const bf16x8*>(bh + bufoff + col * 256 + sg * 8);
#pragma unroll
                for (int m = 0; m < 2; ++m) {
                    acc[m][n] = __builtin_amdgcn_mfma_f32_16x16x32_bf16(a_hi[m][ks], bh8, acc[m][n], 0, 0, 0);
                    acc[m][n] = __builtin_amdgcn_mfma_f32_16x16x32_bf16(a_lo[m][ks], bh8, acc[m][n], 0, 0, 0);
                }
            }
        }

        // ---- approx scores + running top-2 (acc row = kg*4+r, col = r16) ----
#pragma unroll
        for (int n = 0; n < 2; ++n) {
            const int colg = ch * 64 + wc * 32 + n * 16 + r16;
            const float c2v = C2np[colg];
#pragma unroll
            for (int m = 0; m < 2; ++m)
#pragma unroll
                for (int r = 0; r < 4; ++r) {
                    float d = __builtin_fmaf(-2.f, acc[m][n][r], c2v);
                    const bool lt1 = d < v1[m][r];
                    const bool lt2 = d < v2[m][r];
                    v2[m][r] = lt1 ? v1[m][r] : (lt2 ? d : v2[m][r]);
                    i2[m][r] = lt1 ? i1[m][r] : (lt2 ? colg : i2[m][r]);
                    v1[m][r] = lt1 ? d : v1[m][r];
                    i1[m][r] = lt1 ? colg : i1[m][r];
                }
        }
        __syncthreads();
    }
#undef STAGE

    // ---- dump 64 candidates/row to LDS (bufs dead; stride CSTR=65) ----
    float* candV = reinterpret_cast<float*>(lds_raw);              // [64][65]
    int*   candI = reinterpret_cast<int*>(lds_raw + 64 * CSTR * 4);// [64][65]
    int*   winIdx = reinterpret_cast<int*>(lds_raw + 2 * 64 * CSTR * 4);  // [64]
#pragma unroll
    for (int m = 0; m < 2; ++m)
#pragma unroll
        for (int r = 0; r < 4; ++r) {
            const int rl = wr * 32 + m * 16 + kg * 4 + r;
            const int p = wc * 32 + r16 * 2;
            candV[rl * CSTR + p]     = v1[m][r];  candI[rl * CSTR + p]     = i1[m][r];
            candV[rl * CSTR + p + 1] = v2[m][r];  candI[rl * CSTR + p + 1] = i2[m][r];
        }
    __syncthreads();

    // ---- wave 0: per row, window-filter + replicated-fp32 rescore ----
    if (t < 64) {
        float mmin = candV[t * CSTR];
        for (int p = 1; p < 64; ++p) mmin = fminf(mmin, candV[t * CSTR + p]);
        const float wlim = mmin + WINDOW;
        const int grow = blk * 64 + t;
        const float L2v = L2np[grow];
        const float4* x4 = reinterpret_cast<const float4*>(x) + (size_t)grow * 64;
        uint64_t best = ~0ull;
        for (int p = 0; p < 64; ++p) {
            if (candV[t * CSTR + p] <= wlim) {
                const int k = candI[t * CSTR + p];
                const float4* e4 = reinterpret_cast<const float4*>(e) + (size_t)k * 64;
                uint64_t pk = precise_pack(x4, e4, L2v, C2np[k], k);
                best = best < pk ? best : pk;
            }
        }
        winIdx[t] = (int)(best & 0xffffffffu);
    }
    __syncthreads();

    // ---- gather winning codebook rows ----
    const float4* ef4 = reinterpret_cast<const float4*>(e);
    float4* of4 = reinterpret_cast<float4*>(out) + (size_t)blk * 64 * 64;
    for (int i = t; i < 64 * 64; i += 256) {
        const int row = i >> 6, c4 = i & 63;
        of4[i] = ef4[(size_t)winIdx[row] * 64 + c4];
    }
}

extern "C" void kernel_launch(void* const* d_in, const int* in_sizes, int n_in,
                              void* d_out, int out_size, void* d_ws, size_t ws_size,
                              hipStream_t stream) {
    const float* x = (const float*)d_in[0];
    const float* e = (const float*)d_in[1];
    char* ws = (char*)d_ws;
    short* ehi  = (short*)ws;                                   // 2 MB
    float* C2np = (float*)(ws + (size_t)K_CB * D_DIM * 2);      // 16 KB
    float* L2np = (float*)(ws + (size_t)K_CB * D_DIM * 2 + K_CB * 4);  // 128 KB
    float* out = (float*)d_out;

    prep_emb<<<K_CB, 64, 0, stream>>>(e, ehi);
    prep_np<<<(N_ROWS + K_CB + 255) / 256, 256, 0, stream>>>(x, e, L2np, C2np);
    vq_main<<<N_ROWS / 64, 256, 0, stream>>>(x, e, ehi, C2np, L2np, out);
}